// Round 12
// baseline (67.900 us; speedup 1.0000x reference)
//
#include <hip/hip_runtime.h>
#include <hip/hip_fp16.h>
#include <math.h>

#define NB  4
#define DD  128
#define HH  128
#define WW  128
#define KS  11
#define PAD 5
#define NF  4             // fields: xbar, ybar, xybar, (x2+y2)bar
#define ZCK 16            // z outputs per K1 block (8 chunks)
#define HCK 16            // h outputs per K2 block (8 chunks)
#define RW  144           // padded LDS row length (floats)
#define LOFF 6            // w-coord u lives at LDS slot LOFF+u

// Packed intermediate layout: A[n][z][h][q][f*2] fp16 (q = w-pair).
// One 16B vector holds all 4 fields for a w-pair -> 1 load/store per voxel-pair.
#define QS      8                 // halfs per q-slot (4 fields x 2 voxels)
#define HROW    (64 * QS)         // 512 halfs per h row
#define ZPLANE  (HH * HROW)       // 65536 halfs per z plane

using f32x2 = __attribute__((ext_vector_type(2))) float;

struct GW { float g[KS]; };

static __device__ __forceinline__ f32x2 vfma2(f32x2 a, f32x2 b, f32x2 c) {
    return __builtin_elementwise_fma(a, b, c);
}
static __device__ __forceinline__ unsigned h2u(__half2 v) {
    union { __half2 h; unsigned u; } x; x.h = v; return x.u;
}
static __device__ __forceinline__ f32x2 u2f2(unsigned u) {
    union { unsigned u; __half2 h; } x; x.u = u;
    const float2 f = __half22float2(x.h);
    return (f32x2){f.x, f.y};
}

// Wave-local LDS ordering fence: compile-time memory barrier + lgkm drain.
// Does NOT touch vmcnt (global prefetch stays in flight), does NOT sync waves.
#define WAVE_LDS_FENCE() asm volatile("s_waitcnt lgkmcnt(0)" ::: "memory")

// ---------------------------------------------------------------------------
// K1: fields + W-conv + D-conv fused, 2 w-voxels per thread.
// SINGLE-WAVE BLOCKS (64 thr): block = one h-row, walks 16 z (+10 warm).
// 16 blocks/CU resident (LDS 4.6KB, VGPR ~80) -> 16 waves/CU with perfect
// load-balance granularity. Barrier-free: wave owns its LDS rows; cross-lane
// write->read ordering enforced by WAVE_LDS_FENCE() per step. Ping-pong LDS,
// 2-deep float2 prefetch, unroll-by-2, packed f32x2 D-chains, one dwordx4
// store per step.
// ---------------------------------------------------------------------------
__global__ __launch_bounds__(64)
void k1_wd(const float* __restrict__ img1, const float* __restrict__ img2,
           __half* __restrict__ A, GW gw) {
    __shared__ alignas(16) float srow[2][2][RW];   // [buf][img][slot]
    const int q  = threadIdx.x;    // w-pair == lane
    const int b  = blockIdx.x;
    const int h  = b & 127;
    const int zc = (b >> 7) & 7;
    const int n  = b >> 10;
    const int w0 = q * 2;
    const int z0 = zc * ZCK;

    // wave-local pad init: lanes 0..47 zero the 2(buf)x2(img)x12 pad slots
    if (q < 48) {
        const int grp = q / 12, s12 = q % 12;      // grp = [buf][img]
        const int slot = (s12 < 6) ? s12 : (128 + s12);
        srow[grp >> 1][grp & 1][slot] = 0.f;
    }

    const long long inBase  = (long long)n * DD * HH * WW +
                              (long long)h * WW + w0;
    const long long outBase = (long long)n * DD * ZPLANE +
                              (long long)h * HROW + (long long)q * QS;

    f32x2 acc[NF][KS];
    #pragma unroll
    for (int f = 0; f < NF; ++f)
        #pragma unroll
        for (int j = 0; j < KS; ++j) acc[f][j] = (f32x2){0.f, 0.f};

    const int STEPS = ZCK + 2 * PAD;   // 26

    float2 rx0 = make_float2(0.f, 0.f), ry0 = rx0, rx1 = rx0, ry1 = rx0;
    {
        const int zi0 = z0 - PAD;
        if (zi0 >= 0) {
            const long long off = inBase + (long long)zi0 * (HH * WW);
            rx0 = *(const float2*)(img1 + off);
            ry0 = *(const float2*)(img2 + off);
        }
        const int zi1 = z0 - PAD + 1;
        if (zi1 >= 0) {
            const long long off = inBase + (long long)zi1 * (HH * WW);
            rx1 = *(const float2*)(img1 + off);
            ry1 = *(const float2*)(img2 + off);
        }
    }
    *(float2*)&srow[0][0][LOFF + w0] = rx0;
    *(float2*)&srow[0][1][LOFF + w0] = ry0;
    // no block barrier: wave-local data only; fence at top of each step

    // element e (0..13) = w-coord w0-6+e = slot w0+e
    #define ELV(A2, i) ((i) & 1 ? A2[(i) >> 1].y : A2[(i) >> 1].x)

    #define K1_STEP(S, CUR, NXT, RXC, RYC, RXN, RYN, DOST)                     \
    {                                                                          \
        /* order previous step's ds_writes before this step's ds_reads */      \
        WAVE_LDS_FENCE();                                                      \
        {   /* issue load of plane S+2 into the regs freed last step */        \
            const int zi = z0 - PAD + (S) + 2;                                 \
            float2 lx = make_float2(0.f, 0.f), ly = lx;                        \
            if ((S) + 2 < STEPS && zi >= 0 && zi < DD) {                       \
                const long long off = inBase + (long long)zi * (HH * WW);      \
                lx = *(const float2*)(img1 + off);                             \
                ly = *(const float2*)(img2 + off);                             \
            }                                                                  \
            RXC = lx; RYC = ly;                                                \
        }                                                                      \
        /* load 14 values per image from buf CUR (7 x ds_read_b64 each) */     \
        f32x2 xv2[7], yv2[7];                                                  \
        _Pragma("unroll")                                                      \
        for (int i = 0; i < 7; ++i) {                                          \
            const float2 ax = *(const float2*)&srow[CUR][0][w0 + 2 * i];       \
            const float2 ay = *(const float2*)&srow[CUR][1][w0 + 2 * i];       \
            xv2[i] = (f32x2){ax.x, ax.y};                                      \
            yv2[i] = (f32x2){ay.x, ay.y};                                      \
        }                                                                      \
        /* packed products shared by both voxels */                            \
        f32x2 pv2[7], qv2[7];                                                  \
        _Pragma("unroll")                                                      \
        for (int i = 0; i < 7; ++i) {                                          \
            pv2[i] = xv2[i] * yv2[i];                                          \
            qv2[i] = vfma2(yv2[i], yv2[i], xv2[i] * xv2[i]);                   \
        }                                                                      \
        /* W-conv: vox0 uses elements k+1, vox1 uses k+2 */                    \
        float a0x = 0.f, a0y = 0.f, a1x = 0.f, a1y = 0.f;                      \
        float a2x = 0.f, a2y = 0.f, a3x = 0.f, a3y = 0.f;                      \
        _Pragma("unroll")                                                      \
        for (int k = 0; k < KS; ++k) {                                         \
            const float g = gw.g[k];                                           \
            a0x = fmaf(g, ELV(xv2, k + 1), a0x);                               \
            a0y = fmaf(g, ELV(xv2, k + 2), a0y);                               \
            a1x = fmaf(g, ELV(yv2, k + 1), a1x);                               \
            a1y = fmaf(g, ELV(yv2, k + 2), a1y);                               \
            a2x = fmaf(g, ELV(pv2, k + 1), a2x);                               \
            a2y = fmaf(g, ELV(pv2, k + 2), a2y);                               \
            a3x = fmaf(g, ELV(qv2, k + 1), a3x);                               \
            a3y = fmaf(g, ELV(qv2, k + 2), a3y);                               \
        }                                                                      \
        /* stage plane S+1 into buf NXT (wave-local; fenced next step) */      \
        *(float2*)&srow[NXT][0][LOFF + w0] = RXN;                              \
        *(float2*)&srow[NXT][1][LOFF + w0] = RYN;                              \
        /* packed D-conv shift-accumulator chains */                           \
        f32x2 v[NF];                                                           \
        v[0] = (f32x2){a0x, a0y}; v[1] = (f32x2){a1x, a1y};                    \
        v[2] = (f32x2){a2x, a2y}; v[3] = (f32x2){a3x, a3y};                    \
        _Pragma("unroll")                                                      \
        for (int f = 0; f < NF; ++f) {                                         \
            _Pragma("unroll")                                                  \
            for (int j = KS - 1; j >= 1; --j) {                                \
                const f32x2 gg = {gw.g[j], gw.g[j]};                           \
                acc[f][j] = vfma2(gg, v[f], acc[f][j - 1]);                    \
            }                                                                  \
            const f32x2 g0 = {gw.g[0], gw.g[0]};                               \
            acc[f][0] = g0 * v[f];                                             \
        }                                                                      \
        if (DOST) {                                                            \
            const int zo = z0 + (S) - 2 * PAD;                                 \
            uint4 pk;                                                          \
            pk.x = h2u(__float22half2_rn(                                      \
                       make_float2(acc[0][KS-1].x, acc[0][KS-1].y)));          \
            pk.y = h2u(__float22half2_rn(                                      \
                       make_float2(acc[1][KS-1].x, acc[1][KS-1].y)));          \
            pk.z = h2u(__float22half2_rn(                                      \
                       make_float2(acc[2][KS-1].x, acc[2][KS-1].y)));          \
            pk.w = h2u(__float22half2_rn(                                      \
                       make_float2(acc[3][KS-1].x, acc[3][KS-1].y)));          \
            *(uint4*)(A + outBase + (long long)zo * ZPLANE) = pk;              \
        }                                                                      \
    }

    for (int s2 = 0; s2 < 2 * PAD; s2 += 2) {          // warmup, no store
        K1_STEP(s2,     0, 1, rx0, ry0, rx1, ry1, 0)
        K1_STEP(s2 + 1, 1, 0, rx1, ry1, rx0, ry0, 0)
    }
    for (int s2 = 2 * PAD; s2 < STEPS; s2 += 2) {      // main, store
        K1_STEP(s2,     0, 1, rx0, ry0, rx1, ry1, 1)
        K1_STEP(s2 + 1, 1, 0, rx1, ry1, rx0, ry0, 1)
    }
    #undef K1_STEP
    #undef ELV
}

// ---------------------------------------------------------------------------
// K2: H-conv (packed f32x2 shift chains) + packed SSIM + wave reduction.
// SINGLE-WAVE BLOCKS (64 thr): block = one (n,z) row set, walks 16 h (+10
// warm). 2 w-voxels per thread; ONE dwordx4 load per step (all 4 fields);
// 2-deep prefetch; rcp+NR division. No LDS staging (A is L2/L3-resident).
// ---------------------------------------------------------------------------
__global__ __launch_bounds__(64)
void k2_hssim(const __half* __restrict__ A, double* __restrict__ partials,
              GW gw) {
    const int q  = threadIdx.x;
    const int b  = blockIdx.x;
    const int z  = b & 127;
    const int hc = (b >> 7) & 7;
    const int n  = b >> 10;
    const int h0 = hc * HCK;

    const long long colBase =
        ((long long)(n * DD + z)) * ZPLANE + (long long)q * QS;

    f32x2 acc[NF][KS];
    #pragma unroll
    for (int f = 0; f < NF; ++f)
        #pragma unroll
        for (int j = 0; j < KS; ++j) acc[f][j] = (f32x2){0.f, 0.f};

    const int STEPS = HCK + 2 * PAD;   // 26

    uint4 pfA = make_uint4(0u, 0u, 0u, 0u), pfB = pfA;
    {
        const int hi0 = h0 - PAD;
        if (hi0 >= 0)
            pfA = *(const uint4*)(A + colBase + (long long)hi0 * HROW);
        const int hi1 = h0 - PAD + 1;
        if (hi1 >= 0)
            pfB = *(const uint4*)(A + colBase + (long long)hi1 * HROW);
    }

    const f32x2 C1v = {1e-4f, 1e-4f}, C2v = {9e-4f, 9e-4f};
    const f32x2 TWO = {2.f, 2.f};
    f32x2 sum = {0.f, 0.f};

    #define K2_STEP(S, PFC, DOSSIM)                                            \
    {                                                                          \
        f32x2 v[NF];                                                           \
        v[0] = u2f2(PFC.x); v[1] = u2f2(PFC.y);                                \
        v[2] = u2f2(PFC.z); v[3] = u2f2(PFC.w);                                \
        {   /* prefetch row S+2 */                                             \
            const int hi = h0 - PAD + (S) + 2;                                 \
            uint4 nv = make_uint4(0u, 0u, 0u, 0u);                             \
            if ((S) + 2 < STEPS && hi >= 0 && hi < HH)                         \
                nv = *(const uint4*)(A + colBase + (long long)hi * HROW);      \
            PFC = nv;                                                          \
        }                                                                      \
        _Pragma("unroll")                                                      \
        for (int f = 0; f < NF; ++f) {                                         \
            _Pragma("unroll")                                                  \
            for (int j = KS - 1; j >= 1; --j) {                                \
                const f32x2 gg = {gw.g[j], gw.g[j]};                           \
                acc[f][j] = vfma2(gg, v[f], acc[f][j - 1]);                    \
            }                                                                  \
            const f32x2 g0 = {gw.g[0], gw.g[0]};                               \
            acc[f][0] = g0 * v[f];                                             \
        }                                                                      \
        if (DOSSIM) {                                                          \
            const f32x2 mu1 = acc[0][KS - 1], mu2 = acc[1][KS - 1];            \
            const f32x2 mu1s = mu1 * mu1, mu2s = mu2 * mu2, mu12 = mu1 * mu2;  \
            const f32x2 sg12 = acc[2][KS - 1] - mu12;                          \
            const f32x2 sgss = acc[3][KS - 1] - mu1s - mu2s;                   \
            const f32x2 num = vfma2(TWO, mu12, C1v) * vfma2(TWO, sg12, C2v);   \
            const f32x2 den = (mu1s + mu2s + C1v) * (sgss + C2v);              \
            f32x2 rr;                                                          \
            rr.x = __builtin_amdgcn_rcpf(den.x);                               \
            rr.y = __builtin_amdgcn_rcpf(den.y);                               \
            rr = rr * vfma2(-den, rr, TWO);   /* 1 NR step */                  \
            sum = vfma2(num, rr, sum);                                         \
        }                                                                      \
    }

    for (int s2 = 0; s2 < 2 * PAD; s2 += 2) {
        K2_STEP(s2,     pfA, 0)
        K2_STEP(s2 + 1, pfB, 0)
    }
    for (int s2 = 2 * PAD; s2 < STEPS; s2 += 2) {
        K2_STEP(s2,     pfA, 1)
        K2_STEP(s2 + 1, pfB, 1)
    }
    #undef K2_STEP

    // wave-level reduction (64 lanes) via shuffles; one double per block
    double s = (double)sum.x + (double)sum.y;
    #pragma unroll
    for (int sft = 32; sft > 0; sft >>= 1)
        s += __shfl_down(s, sft, 64);
    if (q == 0) partials[b] = s;
}

// ---------------------------------------------------------------------------
__global__ __launch_bounds__(256)
void k4_reduce(const double* __restrict__ partials, int nPart,
               float* __restrict__ out) {
    __shared__ double red[256];
    const int t = threadIdx.x;
    double s = 0.0;
    for (int i = t; i < nPart; i += 256) s += partials[i];
    red[t] = s;
    __syncthreads();
    for (int sft = 128; sft > 0; sft >>= 1) {
        if (t < sft) red[t] += red[t + sft];
        __syncthreads();
    }
    if (t == 0) out[0] = (float)(red[0] / (double)((long long)NB * DD * HH * WW));
}

// ---------------------------------------------------------------------------
extern "C" void kernel_launch(void* const* d_in, const int* in_sizes, int n_in,
                              void* d_out, int out_size, void* d_ws, size_t ws_size,
                              hipStream_t stream) {
    const float* img1 = (const float*)d_in[0];
    const float* img2 = (const float*)d_in[1];
    float* out = (float*)d_out;

    GW gw;
    {
        double gs[KS], ssum = 0.0;
        for (int i = 0; i < KS; ++i) {
            const double c = (double)(i - KS / 2);
            gs[i] = exp(-c * c / (2.0 * 1.5 * 1.5));
            ssum += gs[i];
        }
        for (int i = 0; i < KS; ++i) gw.g[i] = (float)(gs[i] / ssum);
    }

    __half* A = (__half*)d_ws;   // [n][z][h][q][f*2] fp16, 67 MB
    double* partials =
        (double*)((char*)d_ws + (long long)NB * DD * ZPLANE * sizeof(__half));

    const int nBlocksK1 = NB * HH * (DD / ZCK);   // 4096 single-wave blocks
    const int nBlocksK2 = NB * DD * (HH / HCK);   // 4096 single-wave blocks

    k1_wd<<<nBlocksK1, 64, 0, stream>>>(img1, img2, A, gw);
    k2_hssim<<<nBlocksK2, 64, 0, stream>>>(A, partials, gw);
    k4_reduce<<<1, 256, 0, stream>>>(partials, nBlocksK2, out);
}

// Round 13
// 61.468 us; speedup vs baseline: 1.1046x; 1.1046x over previous
//
#include <hip/hip_runtime.h>
#include <hip/hip_fp16.h>
#include <math.h>

#define NB  4
#define DD  128
#define HH  128
#define WW  128
#define KS  11
#define PAD 5
#define NF  4             // fields: xbar, ybar, xybar, (x2+y2)bar
#define ZCK 32            // z outputs per K1 block (4 chunks)
#define HCK 32            // h outputs per K2 block (4 chunks)
#define RWI 140           // interleaved (x,y) slots per row: 6 pad + 128 + 6 pad

// Packed intermediate layout: A[n][z][h][q][f*2] fp16 (q = w-pair).
#define QS      8                 // halfs per q-slot (4 fields x 2 voxels)
#define HROW    (64 * QS)         // 512 halfs per h row
#define ZPLANE  (HH * HROW)       // 65536 halfs per z plane

using f32x2 = __attribute__((ext_vector_type(2))) float;

struct GW { float g[KS]; };

static __device__ __forceinline__ f32x2 vfma2(f32x2 a, f32x2 b, f32x2 c) {
    return __builtin_elementwise_fma(a, b, c);
}
static __device__ __forceinline__ unsigned h2u(__half2 v) {
    union { __half2 h; unsigned u; } x; x.h = v; return x.u;
}
static __device__ __forceinline__ f32x2 u2f2(unsigned u) {
    union { unsigned u; __half2 h; } x; x.u = u;
    const float2 f = __half22float2(x.h);
    return (f32x2){f.x, f.y};
}

// Wave-local LDS ordering fence: compile-time memory barrier + lgkm drain.
#define WAVE_LDS_FENCE() asm volatile("s_waitcnt lgkmcnt(0)" ::: "memory")

// ---------------------------------------------------------------------------
// K1: fields + W-conv + D-conv fused, 2 w-voxels per thread.
// SINGLE-WAVE blocks (64 thr) = one h-row each; ZCK=32 (halo 1.31).
// Interleaved (x,y) LDS row: stage = 1 ds_write_b128, window = 7 ds_read_b128
// (8 LDS ops/step, half of R9's 16 -> shorter fence-serialized chain).
// W-conv: xbar/ybar as one packed chain on raw pairs; x^2+y^2 via packed
// squares + horizontal add; xy scalar. D-conv: packed shift-accumulators.
// Barrier-free; WAVE_LDS_FENCE per step; 2-deep prefetch; unroll-by-2.
// NO VGPR cap (R10 lesson: the (256,4) cap caused spills).
// ---------------------------------------------------------------------------
__global__ __launch_bounds__(64)
void k1_wd(const float* __restrict__ img1, const float* __restrict__ img2,
           __half* __restrict__ A, GW gw) {
    __shared__ alignas(16) float srow[2][RWI][2];   // [buf][slot][xy] 4.5KB
    const int q  = threadIdx.x;    // w-pair == lane
    const int b  = blockIdx.x;
    const int h  = b & 127;
    const int zc = (b >> 7) & 3;
    const int n  = b >> 9;
    const int w0 = q * 2;
    const int z0 = zc * ZCK;

    // wave-local pad init: lanes 0..23 zero the 2(buf)x12 pad slots
    if (q < 24) {
        const int buf = q / 12, i12 = q % 12;
        const int slot = (i12 < 6) ? i12 : (128 + i12);   // 0..5, 134..139
        srow[buf][slot][0] = 0.f;
        srow[buf][slot][1] = 0.f;
    }

    const long long inBase  = (long long)n * DD * HH * WW +
                              (long long)h * WW + w0;
    const long long outBase = (long long)n * DD * ZPLANE +
                              (long long)h * HROW + (long long)q * QS;

    // D-chains packed over fields: A=(xbar,ybar), B=(xybar,ssbar); 0/1=voxel.
    f32x2 cA0[KS], cA1[KS], cB0[KS], cB1[KS];
    #pragma unroll
    for (int j = 0; j < KS; ++j) {
        cA0[j] = (f32x2){0.f, 0.f}; cA1[j] = (f32x2){0.f, 0.f};
        cB0[j] = (f32x2){0.f, 0.f}; cB1[j] = (f32x2){0.f, 0.f};
    }

    const int STEPS = ZCK + 2 * PAD;   // 42

    float2 rx0 = make_float2(0.f, 0.f), ry0 = rx0, rx1 = rx0, ry1 = rx0;
    {
        const int zi0 = z0 - PAD;
        if (zi0 >= 0) {
            const long long off = inBase + (long long)zi0 * (HH * WW);
            rx0 = *(const float2*)(img1 + off);
            ry0 = *(const float2*)(img2 + off);
        }
        const int zi1 = z0 - PAD + 1;
        if (zi1 >= 0) {
            const long long off = inBase + (long long)zi1 * (HH * WW);
            rx1 = *(const float2*)(img1 + off);
            ry1 = *(const float2*)(img2 + off);
        }
    }
    {   // stage plane 0 into buf 0: slots w0+6,w0+7 (byte 16q+48, 16B aligned)
        float4 st; st.x = rx0.x; st.y = ry0.x; st.z = rx0.y; st.w = ry0.y;
        *(float4*)&srow[0][w0 + 6][0] = st;
    }

    #define DCHAIN(ACC, V)                                                     \
        _Pragma("unroll")                                                      \
        for (int j = KS - 1; j >= 1; --j) {                                    \
            const f32x2 gg = {gw.g[j], gw.g[j]};                               \
            ACC[j] = vfma2(gg, V, ACC[j - 1]);                                 \
        }                                                                      \
        { const f32x2 g0 = {gw.g[0], gw.g[0]}; ACC[0] = g0 * (V); }

    #define K1_STEP(S, CUR, NXT, RXC, RYC, RXN, RYN, DOST)                     \
    {                                                                          \
        /* order previous step's ds_write before this step's ds_reads */       \
        WAVE_LDS_FENCE();                                                      \
        {   /* issue load of plane S+2 into the regs freed last step */        \
            const int zi = z0 - PAD + (S) + 2;                                 \
            float2 lx = make_float2(0.f, 0.f), ly = lx;                        \
            if ((S) + 2 < STEPS && zi >= 0 && zi < DD) {                       \
                const long long off = inBase + (long long)zi * (HH * WW);      \
                lx = *(const float2*)(img1 + off);                             \
                ly = *(const float2*)(img2 + off);                             \
            }                                                                  \
            RXC = lx; RYC = ly;                                                \
        }                                                                      \
        /* window: 7 ds_read_b128 of interleaved (x,y) pairs, e = 0..13 */     \
        f32x2 pair_[14]; f32x2 qsq_[14]; float pxy_[14];                       \
        _Pragma("unroll")                                                      \
        for (int i = 0; i < 7; ++i) {                                          \
            const float4 v = *(const float4*)&srow[CUR][w0 + 2 * i][0];        \
            pair_[2*i]   = (f32x2){v.x, v.y};                                  \
            pair_[2*i+1] = (f32x2){v.z, v.w};                                  \
            qsq_[2*i]    = pair_[2*i] * pair_[2*i];                            \
            qsq_[2*i+1]  = pair_[2*i+1] * pair_[2*i+1];                        \
            pxy_[2*i]    = v.x * v.y;                                          \
            pxy_[2*i+1]  = v.z * v.w;                                          \
        }                                                                      \
        /* W-conv: vox0 uses e=k+1, vox1 e=k+2 */                              \
        f32x2 c01_0 = {0.f, 0.f}, c01_1 = {0.f, 0.f};                          \
        f32x2 cQ_0  = {0.f, 0.f}, cQ_1  = {0.f, 0.f};                          \
        float c2_0 = 0.f, c2_1 = 0.f;                                          \
        _Pragma("unroll")                                                      \
        for (int k = 0; k < KS; ++k) {                                         \
            const float g = gw.g[k];                                           \
            const f32x2 gg = {g, g};                                           \
            c01_0 = vfma2(gg, pair_[k + 1], c01_0);                            \
            c01_1 = vfma2(gg, pair_[k + 2], c01_1);                            \
            cQ_0  = vfma2(gg, qsq_[k + 1], cQ_0);                              \
            cQ_1  = vfma2(gg, qsq_[k + 2], cQ_1);                              \
            c2_0  = fmaf(g, pxy_[k + 1], c2_0);                                \
            c2_1  = fmaf(g, pxy_[k + 2], c2_1);                                \
        }                                                                      \
        /* stage plane S+1 into buf NXT (wave-local; fenced next step) */      \
        {                                                                      \
            float4 st; st.x = RXN.x; st.y = RYN.x; st.z = RXN.y; st.w = RYN.y; \
            *(float4*)&srow[NXT][w0 + 6][0] = st;                              \
        }                                                                      \
        /* packed D-conv chains */                                             \
        const f32x2 vB0 = {c2_0, cQ_0.x + cQ_0.y};                             \
        const f32x2 vB1 = {c2_1, cQ_1.x + cQ_1.y};                             \
        DCHAIN(cA0, c01_0)                                                     \
        DCHAIN(cA1, c01_1)                                                     \
        DCHAIN(cB0, vB0)                                                       \
        DCHAIN(cB1, vB1)                                                       \
        if (DOST) {                                                            \
            const int zo = z0 + (S) - 2 * PAD;                                 \
            uint4 pk;                                                          \
            pk.x = h2u(__float22half2_rn(                                      \
                       make_float2(cA0[KS-1].x, cA1[KS-1].x)));  /* xbar  */   \
            pk.y = h2u(__float22half2_rn(                                      \
                       make_float2(cA0[KS-1].y, cA1[KS-1].y)));  /* ybar  */   \
            pk.z = h2u(__float22half2_rn(                                      \
                       make_float2(cB0[KS-1].x, cB1[KS-1].x)));  /* xybar */   \
            pk.w = h2u(__float22half2_rn(                                      \
                       make_float2(cB0[KS-1].y, cB1[KS-1].y)));  /* ssbar */   \
            *(uint4*)(A + outBase + (long long)zo * ZPLANE) = pk;              \
        }                                                                      \
    }

    for (int s2 = 0; s2 < 2 * PAD; s2 += 2) {          // warmup, no store
        K1_STEP(s2,     0, 1, rx0, ry0, rx1, ry1, 0)
        K1_STEP(s2 + 1, 1, 0, rx1, ry1, rx0, ry0, 0)
    }
    for (int s2 = 2 * PAD; s2 < STEPS; s2 += 2) {      // main, store
        K1_STEP(s2,     0, 1, rx0, ry0, rx1, ry1, 1)
        K1_STEP(s2 + 1, 1, 0, rx1, ry1, rx0, ry0, 1)
    }
    #undef K1_STEP
    #undef DCHAIN
}

// ---------------------------------------------------------------------------
// K2: R9's known-good form. H-conv (packed f32x2 shift chains) + packed SSIM
// + block reduction. 2 w-voxels per thread; ONE dwordx4 load per step; 2-deep
// prefetch; rcp+NR division. Block = 256 thr = 4 z x 64 q, walks 32 h (+10).
// ---------------------------------------------------------------------------
__global__ __launch_bounds__(256)
void k2_hssim(const __half* __restrict__ A, double* __restrict__ partials,
              GW gw) {
    const int t  = threadIdx.x;
    const int b  = blockIdx.x;
    const int hc = b & 3;
    const int zp = (b >> 2) & 31;
    const int n  = b >> 7;
    const int zl = t >> 6;
    const int q  = t & 63;
    const int z  = zp * 4 + zl;
    const int h0 = hc * HCK;

    const long long colBase =
        ((long long)(n * DD + z)) * ZPLANE + (long long)q * QS;

    f32x2 acc[NF][KS];
    #pragma unroll
    for (int f = 0; f < NF; ++f)
        #pragma unroll
        for (int j = 0; j < KS; ++j) acc[f][j] = (f32x2){0.f, 0.f};

    const int STEPS = HCK + 2 * PAD;   // 42

    uint4 pfA = make_uint4(0u, 0u, 0u, 0u), pfB = pfA;
    {
        const int hi0 = h0 - PAD;
        if (hi0 >= 0)
            pfA = *(const uint4*)(A + colBase + (long long)hi0 * HROW);
        const int hi1 = h0 - PAD + 1;
        if (hi1 >= 0)
            pfB = *(const uint4*)(A + colBase + (long long)hi1 * HROW);
    }

    const f32x2 C1v = {1e-4f, 1e-4f}, C2v = {9e-4f, 9e-4f};
    const f32x2 TWO = {2.f, 2.f};
    f32x2 sum = {0.f, 0.f};

    #define K2_STEP(S, PFC, DOSSIM)                                            \
    {                                                                          \
        f32x2 v[NF];                                                           \
        v[0] = u2f2(PFC.x); v[1] = u2f2(PFC.y);                                \
        v[2] = u2f2(PFC.z); v[3] = u2f2(PFC.w);                                \
        {   /* prefetch row S+2 */                                             \
            const int hi = h0 - PAD + (S) + 2;                                 \
            uint4 nv = make_uint4(0u, 0u, 0u, 0u);                             \
            if ((S) + 2 < STEPS && hi >= 0 && hi < HH)                         \
                nv = *(const uint4*)(A + colBase + (long long)hi * HROW);      \
            PFC = nv;                                                          \
        }                                                                      \
        _Pragma("unroll")                                                      \
        for (int f = 0; f < NF; ++f) {                                         \
            _Pragma("unroll")                                                  \
            for (int j = KS - 1; j >= 1; --j) {                                \
                const f32x2 gg = {gw.g[j], gw.g[j]};                           \
                acc[f][j] = vfma2(gg, v[f], acc[f][j - 1]);                    \
            }                                                                  \
            const f32x2 g0 = {gw.g[0], gw.g[0]};                               \
            acc[f][0] = g0 * v[f];                                             \
        }                                                                      \
        if (DOSSIM) {                                                          \
            const f32x2 mu1 = acc[0][KS - 1], mu2 = acc[1][KS - 1];            \
            const f32x2 mu1s = mu1 * mu1, mu2s = mu2 * mu2, mu12 = mu1 * mu2;  \
            const f32x2 sg12 = acc[2][KS - 1] - mu12;                          \
            const f32x2 sgss = acc[3][KS - 1] - mu1s - mu2s;                   \
            const f32x2 num = vfma2(TWO, mu12, C1v) * vfma2(TWO, sg12, C2v);   \
            const f32x2 den = (mu1s + mu2s + C1v) * (sgss + C2v);              \
            f32x2 rr;                                                          \
            rr.x = __builtin_amdgcn_rcpf(den.x);                               \
            rr.y = __builtin_amdgcn_rcpf(den.y);                               \
            rr = rr * vfma2(-den, rr, TWO);   /* 1 NR step */                  \
            sum = vfma2(num, rr, sum);                                         \
        }                                                                      \
    }

    for (int s2 = 0; s2 < 2 * PAD; s2 += 2) {
        K2_STEP(s2,     pfA, 0)
        K2_STEP(s2 + 1, pfB, 0)
    }
    for (int s2 = 2 * PAD; s2 < STEPS; s2 += 2) {
        K2_STEP(s2,     pfA, 1)
        K2_STEP(s2 + 1, pfB, 1)
    }
    #undef K2_STEP

    __shared__ double red[256];
    red[t] = (double)sum.x + (double)sum.y;
    __syncthreads();
    for (int sft = 128; sft > 0; sft >>= 1) {
        if (t < sft) red[t] += red[t + sft];
        __syncthreads();
    }
    if (t == 0) partials[b] = red[0];
}

// ---------------------------------------------------------------------------
__global__ __launch_bounds__(256)
void k4_reduce(const double* __restrict__ partials, int nPart,
               float* __restrict__ out) {
    __shared__ double red[256];
    const int t = threadIdx.x;
    double s = 0.0;
    for (int i = t; i < nPart; i += 256) s += partials[i];
    red[t] = s;
    __syncthreads();
    for (int sft = 128; sft > 0; sft >>= 1) {
        if (t < sft) red[t] += red[t + sft];
        __syncthreads();
    }
    if (t == 0) out[0] = (float)(red[0] / (double)((long long)NB * DD * HH * WW));
}

// ---------------------------------------------------------------------------
extern "C" void kernel_launch(void* const* d_in, const int* in_sizes, int n_in,
                              void* d_out, int out_size, void* d_ws, size_t ws_size,
                              hipStream_t stream) {
    const float* img1 = (const float*)d_in[0];
    const float* img2 = (const float*)d_in[1];
    float* out = (float*)d_out;

    GW gw;
    {
        double gs[KS], ssum = 0.0;
        for (int i = 0; i < KS; ++i) {
            const double c = (double)(i - KS / 2);
            gs[i] = exp(-c * c / (2.0 * 1.5 * 1.5));
            ssum += gs[i];
        }
        for (int i = 0; i < KS; ++i) gw.g[i] = (float)(gs[i] / ssum);
    }

    __half* A = (__half*)d_ws;   // [n][z][h][q][f*2] fp16, 67 MB
    double* partials =
        (double*)((char*)d_ws + (long long)NB * DD * ZPLANE * sizeof(__half));

    const int nBlocksK1 = NB * HH * (DD / ZCK);   // 2048 single-wave blocks
    const int nBlocksK2 = NB * 32 * (HH / HCK);   // 512 x 256-thr blocks

    k1_wd<<<nBlocksK1, 64, 0, stream>>>(img1, img2, A, gw);
    k2_hssim<<<nBlocksK2, 256, 0, stream>>>(A, partials, gw);
    k4_reduce<<<1, 256, 0, stream>>>(partials, nBlocksK2, out);
}

// Round 14
// 60.258 us; speedup vs baseline: 1.1268x; 1.0201x over previous
//
#include <hip/hip_runtime.h>
#include <hip/hip_fp16.h>
#include <math.h>

#define NB  4
#define DD  128
#define HH  128
#define WW  128
#define KS  11
#define PAD 5
#define NF  4             // fields: xbar, ybar, xybar, (x2+y2)bar
#define ZCK 32            // z outputs per K1 block (4 chunks)
#define HCK 32            // h outputs per K2 block (4 chunks)
#define RW  144           // padded LDS row length (floats)
#define LOFF 6            // w-coord u lives at LDS slot LOFF+u

// Packed intermediate layout: A[n][z][h][q][f*2] fp16 (q = w-pair).
#define QS      8                 // halfs per q-slot (4 fields x 2 voxels)
#define HROW    (64 * QS)         // 512 halfs per h row
#define ZPLANE  (HH * HROW)       // 65536 halfs per z plane

using f32x2 = __attribute__((ext_vector_type(2))) float;

struct GW { float g[KS]; };

static __device__ __forceinline__ f32x2 vfma2(f32x2 a, f32x2 b, f32x2 c) {
    return __builtin_elementwise_fma(a, b, c);
}
static __device__ __forceinline__ unsigned h2u(__half2 v) {
    union { __half2 h; unsigned u; } x; x.h = v; return x.u;
}
static __device__ __forceinline__ f32x2 u2f2(unsigned u) {
    union { unsigned u; __half2 h; } x; x.u = u;
    const float2 f = __half22float2(x.h);
    return (f32x2){f.x, f.y};
}

// Wave-local LDS ordering fence: compile-time memory barrier + lgkm drain.
#define WAVE_LDS_FENCE() asm volatile("s_waitcnt lgkmcnt(0)" ::: "memory")

// ---------------------------------------------------------------------------
// K1: fields + W-conv + D-conv fused, 2 w-voxels per thread, single-wave
// blocks (64 thr = one h-row), ZCK=32. R9's proven split x/y float2 LDS
// layout (2-way bank aliasing = free; R13's float4 layout was 8-way).
// NEW: 4-deep LDS buffers (plane p -> buf p%4), ONE fence per 2 steps,
// global loads consumed a full iteration after issue (2 compute steps of
// latency cover). All buffer indices compile-time via macro args.
// ---------------------------------------------------------------------------
__global__ __launch_bounds__(64)
void k1_wd(const float* __restrict__ img1, const float* __restrict__ img2,
           __half* __restrict__ A, GW gw) {
    __shared__ alignas(16) float srow[4][2][RW];   // [buf][img][slot] 4.6KB
    const int q  = threadIdx.x;    // w-pair == lane
    const int b  = blockIdx.x;
    const int h  = b & 127;
    const int zc = (b >> 7) & 3;
    const int n  = b >> 9;
    const int w0 = q * 2;
    const int z0 = zc * ZCK;

    // wave-local pad init: lanes 0..47 zero 4(buf)x2(img)x12 pad slots
    if (q < 48) {
        const int grp = q / 12, s12 = q % 12;      // grp = [buf01][img]
        const int slot = (s12 < 6) ? s12 : (128 + s12);
        srow[grp >> 1][grp & 1][slot] = 0.f;
        srow[2 + (grp >> 1)][grp & 1][slot] = 0.f;
    }

    const long long inBase  = (long long)n * DD * HH * WW +
                              (long long)h * WW + w0;
    const long long outBase = (long long)n * DD * ZPLANE +
                              (long long)h * HROW + (long long)q * QS;

    f32x2 acc[NF][KS];
    #pragma unroll
    for (int f = 0; f < NF; ++f)
        #pragma unroll
        for (int j = 0; j < KS; ++j) acc[f][j] = (f32x2){0.f, 0.f};

    const int STEPS = ZCK + 2 * PAD;   // 42

    const float2 FZ = make_float2(0.f, 0.f);
    // load planes 0,1 (z = z0-5, z0-4; never >= DD)
    float2 sx0 = FZ, sy0 = FZ, sx1 = FZ, sy1 = FZ;
    {
        const int zi0 = z0 - PAD;
        if (zi0 >= 0) {
            const long long off = inBase + (long long)zi0 * (HH * WW);
            sx0 = *(const float2*)(img1 + off);
            sy0 = *(const float2*)(img2 + off);
        }
        const int zi1 = z0 - PAD + 1;
        if (zi1 >= 0) {
            const long long off = inBase + (long long)zi1 * (HH * WW);
            sx1 = *(const float2*)(img1 + off);
            sy1 = *(const float2*)(img2 + off);
        }
    }
    // stage planes 0,1 into bufs 0,1
    *(float2*)&srow[0][0][LOFF + w0] = sx0;
    *(float2*)&srow[0][1][LOFF + w0] = sy0;
    *(float2*)&srow[1][0][LOFF + w0] = sx1;
    *(float2*)&srow[1][1][LOFF + w0] = sy1;
    // load planes 2,3 into pend
    float2 p2x = FZ, p2y = FZ, p3x = FZ, p3y = FZ;
    {
        const int zi2 = z0 - PAD + 2;
        if (zi2 >= 0 && zi2 < DD) {
            const long long off = inBase + (long long)zi2 * (HH * WW);
            p2x = *(const float2*)(img1 + off);
            p2y = *(const float2*)(img2 + off);
        }
        const int zi3 = z0 - PAD + 3;
        if (zi3 >= 0 && zi3 < DD) {
            const long long off = inBase + (long long)zi3 * (HH * WW);
            p3x = *(const float2*)(img1 + off);
            p3y = *(const float2*)(img2 + off);
        }
    }

    // element e (0..13) = w-coord w0-6+e = slot w0+e
    #define ELV(A2, i) ((i) & 1 ? A2[(i) >> 1].y : A2[(i) >> 1].x)

    // one compute step: read window from BUF, W-conv, D-chains, store
    #define STEPBODY(S, BUF, DOST)                                             \
    {                                                                          \
        f32x2 xv2[7], yv2[7];                                                  \
        _Pragma("unroll")                                                      \
        for (int i = 0; i < 7; ++i) {                                          \
            const float2 ax = *(const float2*)&srow[BUF][0][w0 + 2 * i];       \
            const float2 ay = *(const float2*)&srow[BUF][1][w0 + 2 * i];       \
            xv2[i] = (f32x2){ax.x, ax.y};                                      \
            yv2[i] = (f32x2){ay.x, ay.y};                                      \
        }                                                                      \
        f32x2 pv2[7], qv2[7];                                                  \
        _Pragma("unroll")                                                      \
        for (int i = 0; i < 7; ++i) {                                          \
            pv2[i] = xv2[i] * yv2[i];                                          \
            qv2[i] = vfma2(yv2[i], yv2[i], xv2[i] * xv2[i]);                   \
        }                                                                      \
        float a0x = 0.f, a0y = 0.f, a1x = 0.f, a1y = 0.f;                      \
        float a2x = 0.f, a2y = 0.f, a3x = 0.f, a3y = 0.f;                      \
        _Pragma("unroll")                                                      \
        for (int k = 0; k < KS; ++k) {                                         \
            const float g = gw.g[k];                                           \
            a0x = fmaf(g, ELV(xv2, k + 1), a0x);                               \
            a0y = fmaf(g, ELV(xv2, k + 2), a0y);                               \
            a1x = fmaf(g, ELV(yv2, k + 1), a1x);                               \
            a1y = fmaf(g, ELV(yv2, k + 2), a1y);                               \
            a2x = fmaf(g, ELV(pv2, k + 1), a2x);                               \
            a2y = fmaf(g, ELV(pv2, k + 2), a2y);                               \
            a3x = fmaf(g, ELV(qv2, k + 1), a3x);                               \
            a3y = fmaf(g, ELV(qv2, k + 2), a3y);                               \
        }                                                                      \
        f32x2 v[NF];                                                           \
        v[0] = (f32x2){a0x, a0y}; v[1] = (f32x2){a1x, a1y};                    \
        v[2] = (f32x2){a2x, a2y}; v[3] = (f32x2){a3x, a3y};                    \
        _Pragma("unroll")                                                      \
        for (int f = 0; f < NF; ++f) {                                         \
            _Pragma("unroll")                                                  \
            for (int j = KS - 1; j >= 1; --j) {                                \
                const f32x2 gg = {gw.g[j], gw.g[j]};                           \
                acc[f][j] = vfma2(gg, v[f], acc[f][j - 1]);                    \
            }                                                                  \
            const f32x2 g0 = {gw.g[0], gw.g[0]};                               \
            acc[f][0] = g0 * v[f];                                             \
        }                                                                      \
        if (DOST) {                                                            \
            const int zo = z0 + (S) - 2 * PAD;                                 \
            uint4 pk;                                                          \
            pk.x = h2u(__float22half2_rn(                                      \
                       make_float2(acc[0][KS-1].x, acc[0][KS-1].y)));          \
            pk.y = h2u(__float22half2_rn(                                      \
                       make_float2(acc[1][KS-1].x, acc[1][KS-1].y)));          \
            pk.z = h2u(__float22half2_rn(                                      \
                       make_float2(acc[2][KS-1].x, acc[2][KS-1].y)));          \
            pk.w = h2u(__float22half2_rn(                                      \
                       make_float2(acc[3][KS-1].x, acc[3][KS-1].y)));          \
            *(uint4*)(A + outBase + (long long)zo * ZPLANE) = pk;              \
        }                                                                      \
    }

    // one iteration = fence + stage 2 pend planes + load 2 + 2 compute steps
    #define K1_ITER(S, RA, RB, WA, WB, DOST)                                   \
    {                                                                          \
        WAVE_LDS_FENCE();   /* covers previous iteration's ds_writes */        \
        *(float2*)&srow[WA][0][LOFF + w0] = p2x;                               \
        *(float2*)&srow[WA][1][LOFF + w0] = p2y;                               \
        *(float2*)&srow[WB][0][LOFF + w0] = p3x;                               \
        *(float2*)&srow[WB][1][LOFF + w0] = p3y;                               \
        {   /* load planes S+4, S+5 into pend (consumed next iteration) */     \
            const int zi4 = z0 - PAD + (S) + 4;                                \
            float2 lx = FZ, ly = FZ;                                           \
            if ((S) + 4 < STEPS && zi4 >= 0 && zi4 < DD) {                     \
                const long long off = inBase + (long long)zi4 * (HH * WW);     \
                lx = *(const float2*)(img1 + off);                             \
                ly = *(const float2*)(img2 + off);                             \
            }                                                                  \
            p2x = lx; p2y = ly;                                                \
        }                                                                      \
        {                                                                      \
            const int zi5 = z0 - PAD + (S) + 5;                                \
            float2 lx = FZ, ly = FZ;                                           \
            if ((S) + 5 < STEPS && zi5 >= 0 && zi5 < DD) {                     \
                const long long off = inBase + (long long)zi5 * (HH * WW);     \
                lx = *(const float2*)(img1 + off);                             \
                ly = *(const float2*)(img2 + off);                             \
            }                                                                  \
            p3x = lx; p3y = ly;                                                \
        }                                                                      \
        STEPBODY((S),     RA, DOST)                                            \
        STEPBODY((S) + 1, RB, DOST)                                            \
    }

    // warmup: steps 0..9, no store
    K1_ITER(0, 0, 1, 2, 3, 0)
    K1_ITER(2, 2, 3, 0, 1, 0)
    K1_ITER(4, 0, 1, 2, 3, 0)
    K1_ITER(6, 2, 3, 0, 1, 0)
    K1_ITER(8, 0, 1, 2, 3, 0)
    // main: steps 10..41, store
    for (int s = 10; s < STEPS; s += 4) {
        K1_ITER(s,     2, 3, 0, 1, 1)
        K1_ITER(s + 2, 0, 1, 2, 3, 1)
    }
    #undef K1_ITER
    #undef STEPBODY
    #undef ELV
}

// ---------------------------------------------------------------------------
// K2: R9's known-good form. H-conv (packed f32x2 shift chains) + packed SSIM
// + block reduction. 2 w-voxels per thread; ONE dwordx4 load per step; 2-deep
// prefetch; rcp+NR division. Block = 256 thr = 4 z x 64 q, walks 32 h (+10).
// ---------------------------------------------------------------------------
__global__ __launch_bounds__(256)
void k2_hssim(const __half* __restrict__ A, double* __restrict__ partials,
              GW gw) {
    const int t  = threadIdx.x;
    const int b  = blockIdx.x;
    const int hc = b & 3;
    const int zp = (b >> 2) & 31;
    const int n  = b >> 7;
    const int zl = t >> 6;
    const int q  = t & 63;
    const int z  = zp * 4 + zl;
    const int h0 = hc * HCK;

    const long long colBase =
        ((long long)(n * DD + z)) * ZPLANE + (long long)q * QS;

    f32x2 acc[NF][KS];
    #pragma unroll
    for (int f = 0; f < NF; ++f)
        #pragma unroll
        for (int j = 0; j < KS; ++j) acc[f][j] = (f32x2){0.f, 0.f};

    const int STEPS = HCK + 2 * PAD;   // 42

    uint4 pfA = make_uint4(0u, 0u, 0u, 0u), pfB = pfA;
    {
        const int hi0 = h0 - PAD;
        if (hi0 >= 0)
            pfA = *(const uint4*)(A + colBase + (long long)hi0 * HROW);
        const int hi1 = h0 - PAD + 1;
        if (hi1 >= 0)
            pfB = *(const uint4*)(A + colBase + (long long)hi1 * HROW);
    }

    const f32x2 C1v = {1e-4f, 1e-4f}, C2v = {9e-4f, 9e-4f};
    const f32x2 TWO = {2.f, 2.f};
    f32x2 sum = {0.f, 0.f};

    #define K2_STEP(S, PFC, DOSSIM)                                            \
    {                                                                          \
        f32x2 v[NF];                                                           \
        v[0] = u2f2(PFC.x); v[1] = u2f2(PFC.y);                                \
        v[2] = u2f2(PFC.z); v[3] = u2f2(PFC.w);                                \
        {   /* prefetch row S+2 */                                             \
            const int hi = h0 - PAD + (S) + 2;                                 \
            uint4 nv = make_uint4(0u, 0u, 0u, 0u);                             \
            if ((S) + 2 < STEPS && hi >= 0 && hi < HH)                         \
                nv = *(const uint4*)(A + colBase + (long long)hi * HROW);      \
            PFC = nv;                                                          \
        }                                                                      \
        _Pragma("unroll")                                                      \
        for (int f = 0; f < NF; ++f) {                                         \
            _Pragma("unroll")                                                  \
            for (int j = KS - 1; j >= 1; --j) {                                \
                const f32x2 gg = {gw.g[j], gw.g[j]};                           \
                acc[f][j] = vfma2(gg, v[f], acc[f][j - 1]);                    \
            }                                                                  \
            const f32x2 g0 = {gw.g[0], gw.g[0]};                               \
            acc[f][0] = g0 * v[f];                                             \
        }                                                                      \
        if (DOSSIM) {                                                          \
            const f32x2 mu1 = acc[0][KS - 1], mu2 = acc[1][KS - 1];            \
            const f32x2 mu1s = mu1 * mu1, mu2s = mu2 * mu2, mu12 = mu1 * mu2;  \
            const f32x2 sg12 = acc[2][KS - 1] - mu12;                          \
            const f32x2 sgss = acc[3][KS - 1] - mu1s - mu2s;                   \
            const f32x2 num = vfma2(TWO, mu12, C1v) * vfma2(TWO, sg12, C2v);   \
            const f32x2 den = (mu1s + mu2s + C1v) * (sgss + C2v);              \
            f32x2 rr;                                                          \
            rr.x = __builtin_amdgcn_rcpf(den.x);                               \
            rr.y = __builtin_amdgcn_rcpf(den.y);                               \
            rr = rr * vfma2(-den, rr, TWO);   /* 1 NR step */                  \
            sum = vfma2(num, rr, sum);                                         \
        }                                                                      \
    }

    for (int s2 = 0; s2 < 2 * PAD; s2 += 2) {
        K2_STEP(s2,     pfA, 0)
        K2_STEP(s2 + 1, pfB, 0)
    }
    for (int s2 = 2 * PAD; s2 < STEPS; s2 += 2) {
        K2_STEP(s2,     pfA, 1)
        K2_STEP(s2 + 1, pfB, 1)
    }
    #undef K2_STEP

    __shared__ double red[256];
    red[t] = (double)sum.x + (double)sum.y;
    __syncthreads();
    for (int sft = 128; sft > 0; sft >>= 1) {
        if (t < sft) red[t] += red[t + sft];
        __syncthreads();
    }
    if (t == 0) partials[b] = red[0];
}

// ---------------------------------------------------------------------------
__global__ __launch_bounds__(256)
void k4_reduce(const double* __restrict__ partials, int nPart,
               float* __restrict__ out) {
    __shared__ double red[256];
    const int t = threadIdx.x;
    double s = 0.0;
    for (int i = t; i < nPart; i += 256) s += partials[i];
    red[t] = s;
    __syncthreads();
    for (int sft = 128; sft > 0; sft >>= 1) {
        if (t < sft) red[t] += red[t + sft];
        __syncthreads();
    }
    if (t == 0) out[0] = (float)(red[0] / (double)((long long)NB * DD * HH * WW));
}

// ---------------------------------------------------------------------------
extern "C" void kernel_launch(void* const* d_in, const int* in_sizes, int n_in,
                              void* d_out, int out_size, void* d_ws, size_t ws_size,
                              hipStream_t stream) {
    const float* img1 = (const float*)d_in[0];
    const float* img2 = (const float*)d_in[1];
    float* out = (float*)d_out;

    GW gw;
    {
        double gs[KS], ssum = 0.0;
        for (int i = 0; i < KS; ++i) {
            const double c = (double)(i - KS / 2);
            gs[i] = exp(-c * c / (2.0 * 1.5 * 1.5));
            ssum += gs[i];
        }
        for (int i = 0; i < KS; ++i) gw.g[i] = (float)(gs[i] / ssum);
    }

    __half* A = (__half*)d_ws;   // [n][z][h][q][f*2] fp16, 67 MB
    double* partials =
        (double*)((char*)d_ws + (long long)NB * DD * ZPLANE * sizeof(__half));

    const int nBlocksK1 = NB * HH * (DD / ZCK);   // 2048 single-wave blocks
    const int nBlocksK2 = NB * 32 * (HH / HCK);   // 512 x 256-thr blocks

    k1_wd<<<nBlocksK1, 64, 0, stream>>>(img1, img2, A, gw);
    k2_hssim<<<nBlocksK2, 256, 0, stream>>>(A, partials, gw);
    k4_reduce<<<1, 256, 0, stream>>>(partials, nBlocksK2, out);
}

// Round 15
// 59.947 us; speedup vs baseline: 1.1327x; 1.0052x over previous
//
#include <hip/hip_runtime.h>
#include <hip/hip_fp16.h>
#include <math.h>

#define NB  4
#define DD  128
#define HH  128
#define WW  128
#define KS  11
#define PAD 5
#define NF  4             // fields: xbar, ybar, xybar, (x2+y2)bar
#define ZCK 32            // z outputs per K1 block (4 chunks)
#define HCK 32            // h outputs per K2 block (4 chunks)
#define RW  144           // padded LDS row length (floats)
#define LOFF 6            // w-coord u lives at LDS slot LOFF+u

// Packed intermediate layout: A[n][z][h][q][f*2] fp16 (q = w-pair).
#define QS      8                 // halfs per q-slot (4 fields x 2 voxels)
#define HROW    (64 * QS)         // 512 halfs per h row
#define ZPLANE  (HH * HROW)       // 65536 halfs per z plane

using f32x2 = __attribute__((ext_vector_type(2))) float;

struct GW { float g[KS]; };

static __device__ __forceinline__ f32x2 vfma2(f32x2 a, f32x2 b, f32x2 c) {
    return __builtin_elementwise_fma(a, b, c);
}
static __device__ __forceinline__ unsigned h2u(__half2 v) {
    union { __half2 h; unsigned u; } x; x.h = v; return x.u;
}
static __device__ __forceinline__ f32x2 u2f2(unsigned u) {
    union { unsigned u; __half2 h; } x; x.u = u;
    const float2 f = __half22float2(x.h);
    return (f32x2){f.x, f.y};
}

// Wave-local LDS ordering fence: compile-time memory barrier + lgkm drain.
#define WAVE_LDS_FENCE() asm volatile("s_waitcnt lgkmcnt(0)" ::: "memory")

// ---------------------------------------------------------------------------
// K1: fields + W-conv + D-conv fused, 2 w-voxels per thread, single-wave
// blocks (64 thr = one h-row), ZCK=32, 4-deep LDS buffers, one fence per
// 2 steps, loads consumed 2 iterations (4 steps) after issue.
// R15 change: __launch_bounds__(64, 1) — lift the VGPR budget so the
// compiler can keep the full 14-read window + products live and issue all
// LDS reads back-to-back instead of serializing them in small batches
// (R14 measured VGPR=104 < ~170 needed; hypothesis: regalloc-forced
// serialization is the 2000cy/step stall).
// ---------------------------------------------------------------------------
__global__ __launch_bounds__(64, 1)
void k1_wd(const float* __restrict__ img1, const float* __restrict__ img2,
           __half* __restrict__ A, GW gw) {
    __shared__ alignas(16) float srow[4][2][RW];   // [buf][img][slot] 4.6KB
    const int q  = threadIdx.x;    // w-pair == lane
    const int b  = blockIdx.x;
    const int h  = b & 127;
    const int zc = (b >> 7) & 3;
    const int n  = b >> 9;
    const int w0 = q * 2;
    const int z0 = zc * ZCK;

    // wave-local pad init: lanes 0..47 zero 4(buf)x2(img)x12 pad slots
    if (q < 48) {
        const int grp = q / 12, s12 = q % 12;      // grp = [buf01][img]
        const int slot = (s12 < 6) ? s12 : (128 + s12);
        srow[grp >> 1][grp & 1][slot] = 0.f;
        srow[2 + (grp >> 1)][grp & 1][slot] = 0.f;
    }

    const long long inBase  = (long long)n * DD * HH * WW +
                              (long long)h * WW + w0;
    const long long outBase = (long long)n * DD * ZPLANE +
                              (long long)h * HROW + (long long)q * QS;

    f32x2 acc[NF][KS];
    #pragma unroll
    for (int f = 0; f < NF; ++f)
        #pragma unroll
        for (int j = 0; j < KS; ++j) acc[f][j] = (f32x2){0.f, 0.f};

    const int STEPS = ZCK + 2 * PAD;   // 42

    const float2 FZ = make_float2(0.f, 0.f);
    // load planes 0,1 (z = z0-5, z0-4; never >= DD)
    float2 sx0 = FZ, sy0 = FZ, sx1 = FZ, sy1 = FZ;
    {
        const int zi0 = z0 - PAD;
        if (zi0 >= 0) {
            const long long off = inBase + (long long)zi0 * (HH * WW);
            sx0 = *(const float2*)(img1 + off);
            sy0 = *(const float2*)(img2 + off);
        }
        const int zi1 = z0 - PAD + 1;
        if (zi1 >= 0) {
            const long long off = inBase + (long long)zi1 * (HH * WW);
            sx1 = *(const float2*)(img1 + off);
            sy1 = *(const float2*)(img2 + off);
        }
    }
    // stage planes 0,1 into bufs 0,1
    *(float2*)&srow[0][0][LOFF + w0] = sx0;
    *(float2*)&srow[0][1][LOFF + w0] = sy0;
    *(float2*)&srow[1][0][LOFF + w0] = sx1;
    *(float2*)&srow[1][1][LOFF + w0] = sy1;
    // load planes 2,3 into pend
    float2 p2x = FZ, p2y = FZ, p3x = FZ, p3y = FZ;
    {
        const int zi2 = z0 - PAD + 2;
        if (zi2 >= 0 && zi2 < DD) {
            const long long off = inBase + (long long)zi2 * (HH * WW);
            p2x = *(const float2*)(img1 + off);
            p2y = *(const float2*)(img2 + off);
        }
        const int zi3 = z0 - PAD + 3;
        if (zi3 >= 0 && zi3 < DD) {
            const long long off = inBase + (long long)zi3 * (HH * WW);
            p3x = *(const float2*)(img1 + off);
            p3y = *(const float2*)(img2 + off);
        }
    }

    // element e (0..13) = w-coord w0-6+e = slot w0+e
    #define ELV(A2, i) ((i) & 1 ? A2[(i) >> 1].y : A2[(i) >> 1].x)

    // one compute step: read window from BUF, W-conv, D-chains, store
    #define STEPBODY(S, BUF, DOST)                                             \
    {                                                                          \
        f32x2 xv2[7], yv2[7];                                                  \
        _Pragma("unroll")                                                      \
        for (int i = 0; i < 7; ++i) {                                          \
            const float2 ax = *(const float2*)&srow[BUF][0][w0 + 2 * i];       \
            const float2 ay = *(const float2*)&srow[BUF][1][w0 + 2 * i];       \
            xv2[i] = (f32x2){ax.x, ax.y};                                      \
            yv2[i] = (f32x2){ay.x, ay.y};                                      \
        }                                                                      \
        f32x2 pv2[7], qv2[7];                                                  \
        _Pragma("unroll")                                                      \
        for (int i = 0; i < 7; ++i) {                                          \
            pv2[i] = xv2[i] * yv2[i];                                          \
            qv2[i] = vfma2(yv2[i], yv2[i], xv2[i] * xv2[i]);                   \
        }                                                                      \
        float a0x = 0.f, a0y = 0.f, a1x = 0.f, a1y = 0.f;                      \
        float a2x = 0.f, a2y = 0.f, a3x = 0.f, a3y = 0.f;                      \
        _Pragma("unroll")                                                      \
        for (int k = 0; k < KS; ++k) {                                         \
            const float g = gw.g[k];                                           \
            a0x = fmaf(g, ELV(xv2, k + 1), a0x);                               \
            a0y = fmaf(g, ELV(xv2, k + 2), a0y);                               \
            a1x = fmaf(g, ELV(yv2, k + 1), a1x);                               \
            a1y = fmaf(g, ELV(yv2, k + 2), a1y);                               \
            a2x = fmaf(g, ELV(pv2, k + 1), a2x);                               \
            a2y = fmaf(g, ELV(pv2, k + 2), a2y);                               \
            a3x = fmaf(g, ELV(qv2, k + 1), a3x);                               \
            a3y = fmaf(g, ELV(qv2, k + 2), a3y);                               \
        }                                                                      \
        f32x2 v[NF];                                                           \
        v[0] = (f32x2){a0x, a0y}; v[1] = (f32x2){a1x, a1y};                    \
        v[2] = (f32x2){a2x, a2y}; v[3] = (f32x2){a3x, a3y};                    \
        _Pragma("unroll")                                                      \
        for (int f = 0; f < NF; ++f) {                                         \
            _Pragma("unroll")                                                  \
            for (int j = KS - 1; j >= 1; --j) {                                \
                const f32x2 gg = {gw.g[j], gw.g[j]};                           \
                acc[f][j] = vfma2(gg, v[f], acc[f][j - 1]);                    \
            }                                                                  \
            const f32x2 g0 = {gw.g[0], gw.g[0]};                               \
            acc[f][0] = g0 * v[f];                                             \
        }                                                                      \
        if (DOST) {                                                            \
            const int zo = z0 + (S) - 2 * PAD;                                 \
            uint4 pk;                                                          \
            pk.x = h2u(__float22half2_rn(                                      \
                       make_float2(acc[0][KS-1].x, acc[0][KS-1].y)));          \
            pk.y = h2u(__float22half2_rn(                                      \
                       make_float2(acc[1][KS-1].x, acc[1][KS-1].y)));          \
            pk.z = h2u(__float22half2_rn(                                      \
                       make_float2(acc[2][KS-1].x, acc[2][KS-1].y)));          \
            pk.w = h2u(__float22half2_rn(                                      \
                       make_float2(acc[3][KS-1].x, acc[3][KS-1].y)));          \
            *(uint4*)(A + outBase + (long long)zo * ZPLANE) = pk;              \
        }                                                                      \
    }

    // one iteration = fence + stage 2 pend planes + load 2 + 2 compute steps
    #define K1_ITER(S, RA, RB, WA, WB, DOST)                                   \
    {                                                                          \
        WAVE_LDS_FENCE();   /* covers previous iteration's ds_writes */        \
        *(float2*)&srow[WA][0][LOFF + w0] = p2x;                               \
        *(float2*)&srow[WA][1][LOFF + w0] = p2y;                               \
        *(float2*)&srow[WB][0][LOFF + w0] = p3x;                               \
        *(float2*)&srow[WB][1][LOFF + w0] = p3y;                               \
        {   /* load planes S+4, S+5 into pend (consumed next iteration) */     \
            const int zi4 = z0 - PAD + (S) + 4;                                \
            float2 lx = FZ, ly = FZ;                                           \
            if ((S) + 4 < STEPS && zi4 >= 0 && zi4 < DD) {                     \
                const long long off = inBase + (long long)zi4 * (HH * WW);     \
                lx = *(const float2*)(img1 + off);                             \
                ly = *(const float2*)(img2 + off);                             \
            }                                                                  \
            p2x = lx; p2y = ly;                                                \
        }                                                                      \
        {                                                                      \
            const int zi5 = z0 - PAD + (S) + 5;                                \
            float2 lx = FZ, ly = FZ;                                           \
            if ((S) + 5 < STEPS && zi5 >= 0 && zi5 < DD) {                     \
                const long long off = inBase + (long long)zi5 * (HH * WW);     \
                lx = *(const float2*)(img1 + off);                             \
                ly = *(const float2*)(img2 + off);                             \
            }                                                                  \
            p3x = lx; p3y = ly;                                                \
        }                                                                      \
        STEPBODY((S),     RA, DOST)                                            \
        STEPBODY((S) + 1, RB, DOST)                                            \
    }

    // warmup: steps 0..9, no store
    K1_ITER(0, 0, 1, 2, 3, 0)
    K1_ITER(2, 2, 3, 0, 1, 0)
    K1_ITER(4, 0, 1, 2, 3, 0)
    K1_ITER(6, 2, 3, 0, 1, 0)
    K1_ITER(8, 0, 1, 2, 3, 0)
    // main: steps 10..41, store
    for (int s = 10; s < STEPS; s += 4) {
        K1_ITER(s,     2, 3, 0, 1, 1)
        K1_ITER(s + 2, 0, 1, 2, 3, 1)
    }
    #undef K1_ITER
    #undef STEPBODY
    #undef ELV
}

// ---------------------------------------------------------------------------
// K2: R9's known-good form. H-conv (packed f32x2 shift chains) + packed SSIM
// + block reduction. 2 w-voxels per thread; ONE dwordx4 load per step; 2-deep
// prefetch; rcp+NR division. Block = 256 thr = 4 z x 64 q, walks 32 h (+10).
// ---------------------------------------------------------------------------
__global__ __launch_bounds__(256)
void k2_hssim(const __half* __restrict__ A, double* __restrict__ partials,
              GW gw) {
    const int t  = threadIdx.x;
    const int b  = blockIdx.x;
    const int hc = b & 3;
    const int zp = (b >> 2) & 31;
    const int n  = b >> 7;
    const int zl = t >> 6;
    const int q  = t & 63;
    const int z  = zp * 4 + zl;
    const int h0 = hc * HCK;

    const long long colBase =
        ((long long)(n * DD + z)) * ZPLANE + (long long)q * QS;

    f32x2 acc[NF][KS];
    #pragma unroll
    for (int f = 0; f < NF; ++f)
        #pragma unroll
        for (int j = 0; j < KS; ++j) acc[f][j] = (f32x2){0.f, 0.f};

    const int STEPS = HCK + 2 * PAD;   // 42

    uint4 pfA = make_uint4(0u, 0u, 0u, 0u), pfB = pfA;
    {
        const int hi0 = h0 - PAD;
        if (hi0 >= 0)
            pfA = *(const uint4*)(A + colBase + (long long)hi0 * HROW);
        const int hi1 = h0 - PAD + 1;
        if (hi1 >= 0)
            pfB = *(const uint4*)(A + colBase + (long long)hi1 * HROW);
    }

    const f32x2 C1v = {1e-4f, 1e-4f}, C2v = {9e-4f, 9e-4f};
    const f32x2 TWO = {2.f, 2.f};
    f32x2 sum = {0.f, 0.f};

    #define K2_STEP(S, PFC, DOSSIM)                                            \
    {                                                                          \
        f32x2 v[NF];                                                           \
        v[0] = u2f2(PFC.x); v[1] = u2f2(PFC.y);                                \
        v[2] = u2f2(PFC.z); v[3] = u2f2(PFC.w);                                \
        {   /* prefetch row S+2 */                                             \
            const int hi = h0 - PAD + (S) + 2;                                 \
            uint4 nv = make_uint4(0u, 0u, 0u, 0u);                             \
            if ((S) + 2 < STEPS && hi >= 0 && hi < HH)                         \
                nv = *(const uint4*)(A + colBase + (long long)hi * HROW);      \
            PFC = nv;                                                          \
        }                                                                      \
        _Pragma("unroll")                                                      \
        for (int f = 0; f < NF; ++f) {                                         \
            _Pragma("unroll")                                                  \
            for (int j = KS - 1; j >= 1; --j) {                                \
                const f32x2 gg = {gw.g[j], gw.g[j]};                           \
                acc[f][j] = vfma2(gg, v[f], acc[f][j - 1]);                    \
            }                                                                  \
            const f32x2 g0 = {gw.g[0], gw.g[0]};                               \
            acc[f][0] = g0 * v[f];                                             \
        }                                                                      \
        if (DOSSIM) {                                                          \
            const f32x2 mu1 = acc[0][KS - 1], mu2 = acc[1][KS - 1];            \
            const f32x2 mu1s = mu1 * mu1, mu2s = mu2 * mu2, mu12 = mu1 * mu2;  \
            const f32x2 sg12 = acc[2][KS - 1] - mu12;                          \
            const f32x2 sgss = acc[3][KS - 1] - mu1s - mu2s;                   \
            const f32x2 num = vfma2(TWO, mu12, C1v) * vfma2(TWO, sg12, C2v);   \
            const f32x2 den = (mu1s + mu2s + C1v) * (sgss + C2v);              \
            f32x2 rr;                                                          \
            rr.x = __builtin_amdgcn_rcpf(den.x);                               \
            rr.y = __builtin_amdgcn_rcpf(den.y);                               \
            rr = rr * vfma2(-den, rr, TWO);   /* 1 NR step */                  \
            sum = vfma2(num, rr, sum);                                         \
        }                                                                      \
    }

    for (int s2 = 0; s2 < 2 * PAD; s2 += 2) {
        K2_STEP(s2,     pfA, 0)
        K2_STEP(s2 + 1, pfB, 0)
    }
    for (int s2 = 2 * PAD; s2 < STEPS; s2 += 2) {
        K2_STEP(s2,     pfA, 1)
        K2_STEP(s2 + 1, pfB, 1)
    }
    #undef K2_STEP

    __shared__ double red[256];
    red[t] = (double)sum.x + (double)sum.y;
    __syncthreads();
    for (int sft = 128; sft > 0; sft >>= 1) {
        if (t < sft) red[t] += red[t + sft];
        __syncthreads();
    }
    if (t == 0) partials[b] = red[0];
}

// ---------------------------------------------------------------------------
__global__ __launch_bounds__(256)
void k4_reduce(const double* __restrict__ partials, int nPart,
               float* __restrict__ out) {
    __shared__ double red[256];
    const int t = threadIdx.x;
    double s = 0.0;
    for (int i = t; i < nPart; i += 256) s += partials[i];
    red[t] = s;
    __syncthreads();
    for (int sft = 128; sft > 0; sft >>= 1) {
        if (t < sft) red[t] += red[t + sft];
        __syncthreads();
    }
    if (t == 0) out[0] = (float)(red[0] / (double)((long long)NB * DD * HH * WW));
}

// ---------------------------------------------------------------------------
extern "C" void kernel_launch(void* const* d_in, const int* in_sizes, int n_in,
                              void* d_out, int out_size, void* d_ws, size_t ws_size,
                              hipStream_t stream) {
    const float* img1 = (const float*)d_in[0];
    const float* img2 = (const float*)d_in[1];
    float* out = (float*)d_out;

    GW gw;
    {
        double gs[KS], ssum = 0.0;
        for (int i = 0; i < KS; ++i) {
            const double c = (double)(i - KS / 2);
            gs[i] = exp(-c * c / (2.0 * 1.5 * 1.5));
            ssum += gs[i];
        }
        for (int i = 0; i < KS; ++i) gw.g[i] = (float)(gs[i] / ssum);
    }

    __half* A = (__half*)d_ws;   // [n][z][h][q][f*2] fp16, 67 MB
    double* partials =
        (double*)((char*)d_ws + (long long)NB * DD * ZPLANE * sizeof(__half));

    const int nBlocksK1 = NB * HH * (DD / ZCK);   // 2048 single-wave blocks
    const int nBlocksK2 = NB * 32 * (HH / HCK);   // 512 x 256-thr blocks

    k1_wd<<<nBlocksK1, 64, 0, stream>>>(img1, img2, A, gw);
    k2_hssim<<<nBlocksK2, 256, 0, stream>>>(A, partials, gw);
    k4_reduce<<<1, 256, 0, stream>>>(partials, nBlocksK2, out);
}